// Round 1
// baseline (926.298 us; speedup 1.0000x reference)
//
#include <hip/hip_runtime.h>

#define PI_D 3.14159265358979323846

#define BATCH   64
#define LWAV    160000
#define NFFT    2048
#define HOP     512
#define NMELS   128
#define NFRAMES 313      // 1 + 160000/512
#define NFREQ   1025     // NFFT/2 + 1
#define PADW    1024     // NFFT/2

// workspace layout (float offsets)
#define OFF_WIN  0        // 2048 window
#define OFF_TWR  2048     // 1024 twiddle cos
#define OFF_TWI  3072     // 1024 twiddle sin
#define OFF_WA   4096     // 2048 weight A (bit-rev order)
#define OFF_WB   6144     // 2048 weight B (bit-rev order)
#define OFF_KIDX 8192     // 2048 packed bin indices (int, bit-rev order)
#define OFF_MEL  10240    // NFRAMES * BATCH * NMELS  (t-major mel buffer)

__global__ __launch_bounds__(256) void init_tables(float* __restrict__ ws) {
    __shared__ double fpts[130];
    const int tid = threadIdx.x;
    // Hann window (f64, matches numpy then cast f32)
    for (int i = tid; i < NFFT; i += 256) {
        double w = 0.5 - 0.5 * cos(2.0 * PI_D * (double)i / (double)NFFT);
        ws[OFF_WIN + i] = (float)w;
    }
    // twiddles W_2048^k = exp(-2*pi*i*k/2048), k = 0..1023
    for (int k = tid; k < 1024; k += 256) {
        double ang = -2.0 * PI_D * (double)k / (double)NFFT;
        ws[OFF_TWR + k] = (float)cos(ang);
        ws[OFF_TWI + k] = (float)sin(ang);
    }
    // mel break points in Hz (f64, mirrors reference construction)
    if (tid < 130) {
        double mlo = 2595.0 * log10(1.0 + 20.0 / 700.0);
        double mhi = 2595.0 * log10(1.0 + 16000.0 / 700.0);
        double m = mlo + (mhi - mlo) * (double)tid / 129.0;
        fpts[tid] = 700.0 * (pow(10.0, m / 2595.0) - 1.0);
    }
    __syncthreads();
    // Sparse filterbank: each freq f contributes to at most filters k and k-1
    // where fpts[k] <= f_hz < fpts[k+1]. Weight = max(0, min(down, up)) exactly
    // as the dense reference. Stored at bit-reversed address a (f = rev11(a))
    // so the FFT epilogue reads linearly.
    int* kidx = (int*)ws + OFF_KIDX;
    for (int a = tid; a < NFFT; a += 256) {
        int f = (int)(__brev((unsigned)a) >> 21);  // rev11
        float wa = 0.f, wb = 0.f;
        int ka = 0, kb = 0;
        if (f < NFREQ) {
            double fhz = (double)f * 15.625;  // (SR/2)/1024, exact
            int k = -1;
            for (int i = 0; i < 130; i++) k += (fpts[i] <= fhz) ? 1 : 0;
            if (k >= 0 && k <= 127) {
                double down = (fhz - fpts[k]) / (fpts[k + 1] - fpts[k]);
                double up   = (fpts[k + 2] - fhz) / (fpts[k + 2] - fpts[k + 1]);
                double w = down < up ? down : up;
                if (w > 0.0) { wa = (float)w; ka = k; }
            }
            int km = k - 1;
            if (km >= 0 && km <= 127) {
                double down = (fhz - fpts[km]) / (fpts[km + 1] - fpts[km]);
                double up   = (fpts[km + 2] - fhz) / (fpts[km + 2] - fpts[km + 1]);
                double w = down < up ? down : up;
                if (w > 0.0) { wb = (float)w; kb = km; }
            }
        }
        ws[OFF_WA + a] = wa;
        ws[OFF_WB + a] = wb;
        kidx[a] = ka | (kb << 16);
    }
}

// One block per (b, t) frame: window -> 2048-pt DIF FFT in LDS -> power ->
// sparse mel scatter via LDS atomics -> write 128 mel values (t-major).
__global__ __launch_bounds__(256) void fft_mel_kernel(const float* __restrict__ wav,
                                                      float* __restrict__ ws) {
    __shared__ float re[NFFT];
    __shared__ float im[NFFT];
    __shared__ float twr[1024];
    __shared__ float twi[1024];
    __shared__ float smel[NMELS];
    const int tid = threadIdx.x;
    const int blk = blockIdx.x;
    const int b = blk / NFRAMES;
    const int t = blk - b * NFRAMES;

    for (int k = tid; k < 1024; k += 256) {
        twr[k] = ws[OFF_TWR + k];
        twi[k] = ws[OFF_TWI + k];
    }
    const float* __restrict__ src = wav + (size_t)b * LWAV;
    const int base = t * HOP - PADW;
#pragma unroll
    for (int j = 0; j < 8; j++) {
        int i = tid + j * 256;
        int pos = base + i;
        pos = pos < 0 ? -pos : pos;                       // reflect left
        pos = pos >= LWAV ? 2 * LWAV - 2 - pos : pos;     // reflect right
        re[i] = src[pos] * ws[OFF_WIN + i];
        im[i] = 0.f;
    }
    if (tid < NMELS) smel[tid] = 0.f;
    __syncthreads();

    // radix-2 DIF: natural-order input, bit-reversed output
    for (int s = 11; s >= 1; s--) {
        const int half = 1 << (s - 1);
        const int tsh = 11 - s;
#pragma unroll
        for (int q = 0; q < 4; q++) {
            int bf = tid + q * 256;
            int j = bf & (half - 1);
            int grp = bf >> (s - 1);
            int pos = (grp << s) + j;
            int p2 = pos + half;
            float ur = re[pos], ui = im[pos];
            float vr = re[p2],  vi = im[p2];
            re[pos] = ur + vr;
            im[pos] = ui + vi;
            float sr = ur - vr, si = ui - vi;
            int ti = j << tsh;
            float wr = twr[ti], wi = twi[ti];
            re[p2] = sr * wr - si * wi;
            im[p2] = sr * wi + si * wr;
        }
        __syncthreads();
    }

    // power + mel scatter. LDS[a] holds X[rev11(a)]; tables are pre-reversed,
    // entries with f >= 1025 have zero weights.
    const float* __restrict__ wA = ws + OFF_WA;
    const float* __restrict__ wB = ws + OFF_WB;
    const int* __restrict__ kidx = (const int*)ws + OFF_KIDX;
#pragma unroll
    for (int j = 0; j < 8; j++) {
        int a = tid + j * 256;
        float rr = re[a], ii = im[a];
        float p = rr * rr + ii * ii;
        int kk = kidx[a];
        atomicAdd(&smel[kk & 0xffff], p * wA[a]);
        atomicAdd(&smel[kk >> 16],    p * wB[a]);
    }
    __syncthreads();
    if (tid < NMELS) {
        ws[OFF_MEL + (size_t)t * (BATCH * NMELS) + b * NMELS + tid] = smel[tid];
    }
}

// One thread per (b, m) series; sequential PCEN scan over time.
__global__ __launch_bounds__(256) void pcen_kernel(const float* __restrict__ ws,
                                                   float* __restrict__ out) {
    const int g = blockIdx.x * 256 + threadIdx.x;  // 0 .. 8191 = b*128 + m
    const float* __restrict__ mel = ws + OFF_MEL;
    float m = 0.f;
    float* __restrict__ o = out + (size_t)g * NFRAMES;
    for (int t = 0; t < NFRAMES; t++) {
        float x = mel[(size_t)t * (BATCH * NMELS) + g];  // coalesced read
        m = 0.975f * m + 0.025f * x;
        float d = 1e-6f + m;
        float p = sqrtf(x * powf(d, -0.98f) + 2.0f) - 1.41421356237f;
        o[t] = p;  // stride-313 store (optimize later if counters say so)
    }
}

extern "C" void kernel_launch(void* const* d_in, const int* in_sizes, int n_in,
                              void* d_out, int out_size, void* d_ws, size_t ws_size,
                              hipStream_t stream) {
    const float* wav = (const float*)d_in[0];
    float* out = (float*)d_out;
    float* ws = (float*)d_ws;
    init_tables<<<1, 256, 0, stream>>>(ws);
    fft_mel_kernel<<<BATCH * NFRAMES, 256, 0, stream>>>(wav, ws);
    pcen_kernel<<<(BATCH * NMELS) / 256, 256, 0, stream>>>(ws, out);
}

// Round 2
// 395.053 us; speedup vs baseline: 2.3447x; 2.3447x over previous
//
#include <hip/hip_runtime.h>

#define PI_D 3.14159265358979323846

#define BATCH   64
#define LWAV    160000
#define NFFT    2048
#define HOP     512
#define NMELS   128
#define NFRAMES 313      // 1 + 160000/512
#define NCPLX   1024     // complex FFT size (real-pack)
#define PADW    1024     // NFFT/2

// workspace layout (float offsets)
#define OFF_WIN  0        // 2048 window (natural order, read as float2)
#define OFF_TBL  2048     // float4[1024]: {kidx(bits), wA, wB, 0} in digit-rev order
#define OFF_MEL  6144     // NFRAMES * BATCH * NMELS  (t-major mel buffer)

// LDS pad-swizzle: +1 float per 32 (breaks power-of-2 stride conflicts)
#define P(i) ((i) + ((i) >> 5))
#define LDSN (NCPLX + NCPLX / 32)   // 1056

__host__ __device__ __forceinline__ int digitrev10(int a) {
    // reverse 5 base-4 digits of a 10-bit index
    return ((a & 3) << 8) | (((a >> 2) & 3) << 6) | (((a >> 4) & 3) << 4) |
           (((a >> 6) & 3) << 2) | ((a >> 8) & 3);
}

__global__ __launch_bounds__(256) void init_tables(float* __restrict__ ws) {
    __shared__ double fpts[130];
    const int tid = threadIdx.x;
    // Hann window (f64, matches numpy, cast f32)
    for (int i = tid; i < NFFT; i += 256) {
        double w = 0.5 - 0.5 * cos(2.0 * PI_D * (double)i / (double)NFFT);
        ws[OFF_WIN + i] = (float)w;
    }
    // mel break points in Hz (f64, mirrors reference construction)
    if (tid < 130) {
        double mlo = 2595.0 * log10(1.0 + 20.0 / 700.0);
        double mhi = 2595.0 * log10(1.0 + 16000.0 / 700.0);
        double m = mlo + (mhi - mlo) * (double)tid / 129.0;
        fpts[tid] = 700.0 * (pow(10.0, m / 2595.0) - 1.0);
    }
    __syncthreads();
    // Sparse filterbank in digit-reversed order: entry a describes freq bin
    // k = digitrev10(a). Bin k contributes to at most filters kf and kf-1.
    // Bins 0 and 1024 have exactly zero weight (f<20Hz / f=16kHz top edge),
    // so covering k=0..1023 is complete.
    float4* tbl = (float4*)(ws + OFF_TBL);
    for (int a = tid; a < NCPLX; a += 256) {
        int k = digitrev10(a);
        double fhz = (double)k * 15.625;  // (SR/2)/1024 exact
        float wa = 0.f, wb = 0.f;
        int ka = 0, kb = 0;
        int kf = -1;
        for (int i = 0; i < 130; i++) kf += (fpts[i] <= fhz) ? 1 : 0;
        if (kf >= 0 && kf <= 127) {
            double down = (fhz - fpts[kf]) / (fpts[kf + 1] - fpts[kf]);
            double up   = (fpts[kf + 2] - fhz) / (fpts[kf + 2] - fpts[kf + 1]);
            double w = down < up ? down : up;
            if (w > 0.0) { wa = (float)w; ka = kf; }
        }
        int km = kf - 1;
        if (km >= 0 && km <= 127) {
            double down = (fhz - fpts[km]) / (fpts[km + 1] - fpts[km]);
            double up   = (fpts[km + 2] - fhz) / (fpts[km + 2] - fpts[km + 1]);
            double w = down < up ? down : up;
            if (w > 0.0) { wb = (float)w; kb = km; }
        }
        float4 v;
        v.x = __int_as_float(ka | (kb << 16));
        v.y = wa; v.z = wb; v.w = 0.f;
        tbl[a] = v;
    }
}

// In-place radix-4 DIF stage on LDS (1 butterfly per thread, 256 threads).
template <int LOG2Q>
__device__ __forceinline__ void r4_stage(float* re, float* im, int tid) {
    const int Q = 1 << LOG2Q;
    const int L = 4 * Q;
    int j = tid & (Q - 1);
    int p = ((tid >> LOG2Q) << (LOG2Q + 2)) + j;
    int p0 = P(p), p1 = P(p + Q), p2 = P(p + 2 * Q), p3 = P(p + 3 * Q);
    float a0r = re[p0], a0i = im[p0];
    float a1r = re[p1], a1i = im[p1];
    float a2r = re[p2], a2i = im[p2];
    float a3r = re[p3], a3i = im[p3];
    float t0r = a0r + a2r, t0i = a0i + a2i;
    float t1r = a0r - a2r, t1i = a0i - a2i;
    float t2r = a1r + a3r, t2i = a1i + a3i;
    float t3r = a1r - a3r, t3i = a1i - a3i;
    re[p0] = t0r + t2r; im[p0] = t0i + t2i;           // y0, W^0
    float ang = (-2.0f * 3.14159265358979f / (float)L) * (float)j;
    float s1, c1;
    __sincosf(ang, &s1, &c1);
    float c2 = c1 * c1 - s1 * s1, s2 = 2.f * c1 * s1; // W^2
    float c3 = c1 * c2 - s1 * s2, s3 = c1 * s2 + s1 * c2; // W^3
    float u1r = t1r + t3i, u1i = t1i - t3r;           // t1 - i*t3
    re[p1] = u1r * c1 - u1i * s1; im[p1] = u1r * s1 + u1i * c1;
    float u2r = t0r - t2r, u2i = t0i - t2i;
    re[p2] = u2r * c2 - u2i * s2; im[p2] = u2r * s2 + u2i * c2;
    float u3r = t1r - t3i, u3i = t1i + t3r;           // t1 + i*t3
    re[p3] = u3r * c3 - u3i * s3; im[p3] = u3r * s3 + u3i * c3;
}

// One block per (b, t) frame: window+pack -> 1024-pt radix-4 DIF FFT in LDS
// -> real-FFT untwist -> power -> sparse mel scatter -> 128 mel out (t-major).
__global__ __launch_bounds__(256) void fft_mel_kernel(const float* __restrict__ wav,
                                                      float* __restrict__ ws) {
    __shared__ float re[LDSN];
    __shared__ float im[LDSN];
    __shared__ float smel[NMELS];
    const int tid = threadIdx.x;
    const int blk = blockIdx.x;
    const int b = blk / NFRAMES;
    const int t = blk - b * NFRAMES;
    const float* __restrict__ src = wav + (size_t)b * LWAV;
    const int base = t * HOP - PADW;   // always even
    const float2* __restrict__ win2 = (const float2*)(ws + OFF_WIN);

    if (base >= 0 && base + NFFT <= LWAV) {
        const float2* __restrict__ s2 = (const float2*)(src + base);
#pragma unroll
        for (int q = 0; q < 4; q++) {
            int n = tid + q * 256;
            float2 xv = s2[n];
            float2 wv = win2[n];
            re[P(n)] = xv.x * wv.x;
            im[P(n)] = xv.y * wv.y;
        }
    } else {
#pragma unroll
        for (int q = 0; q < 4; q++) {
            int n = tid + q * 256;
            int i0 = base + 2 * n, i1 = i0 + 1;
            i0 = i0 < 0 ? -i0 : i0; i0 = i0 >= LWAV ? 2 * LWAV - 2 - i0 : i0;
            i1 = i1 < 0 ? -i1 : i1; i1 = i1 >= LWAV ? 2 * LWAV - 2 - i1 : i1;
            float2 wv = win2[n];
            re[P(n)] = src[i0] * wv.x;
            im[P(n)] = src[i1] * wv.y;
        }
    }
    if (tid < NMELS) smel[tid] = 0.f;
    __syncthreads();

    r4_stage<8>(re, im, tid); __syncthreads();
    r4_stage<6>(re, im, tid); __syncthreads();
    r4_stage<4>(re, im, tid); __syncthreads();
    r4_stage<2>(re, im, tid); __syncthreads();
    r4_stage<0>(re, im, tid); __syncthreads();

    // Untwist + power + mel scatter. LDS addr a holds Z[digitrev10(a)].
    const float4* __restrict__ tbl = (const float4*)(ws + OFF_TBL);
#pragma unroll
    for (int q = 0; q < 4; q++) {
        int a = tid + q * 256;
        int k = digitrev10(a);
        int kp = (NCPLX - k) & (NCPLX - 1);
        int pa = digitrev10(kp);
        float zar = re[P(a)],  zai = im[P(a)];
        float zpr = re[P(pa)], zpi = im[P(pa)];
        float Ar = 0.5f * (zar + zpr), Ai = 0.5f * (zai - zpi);
        float Or = 0.5f * (zai + zpi), Oi = -0.5f * (zar - zpr);
        float ang = (-3.14159265358979f / (float)NCPLX) * (float)k;
        float s, c;
        __sincosf(ang, &s, &c);
        float Xr = Ar + c * Or - s * Oi;
        float Xi = Ai + c * Oi + s * Or;
        float pw = Xr * Xr + Xi * Xi;
        float4 tb = tbl[a];
        int kk = __float_as_int(tb.x);
        atomicAdd(&smel[kk & 0xffff], pw * tb.y);
        atomicAdd(&smel[kk >> 16],    pw * tb.z);
    }
    __syncthreads();
    if (tid < NMELS) {
        ws[OFF_MEL + (size_t)t * (BATCH * NMELS) + b * NMELS + tid] = smel[tid];
    }
}

// One block per batch b: LDS-tiled PCEN. 128 threads = 128 mel chains.
__global__ __launch_bounds__(128) void pcen_kernel(const float* __restrict__ ws,
                                                   float* __restrict__ out) {
    __shared__ float tile[32 * 129];   // +1 pad: conflict-free transpose
    const int b = blockIdx.x;
    const int tid = threadIdx.x;
    const float* __restrict__ mel = ws + OFF_MEL + b * NMELS;
    float m = 0.f;
    for (int t0 = 0; t0 < NFRAMES; t0 += 32) {
        const int nt = (NFRAMES - t0) < 32 ? (NFRAMES - t0) : 32;
        for (int idx = tid; idx < nt * 128; idx += 128) {
            int tt = idx >> 7, mm = idx & 127;
            tile[tt * 129 + mm] = mel[(size_t)(t0 + tt) * (BATCH * NMELS) + mm];
        }
        __syncthreads();
        for (int tt = 0; tt < nt; tt++) {
            float x = tile[tt * 129 + tid];
            m = fmaf(0.975f, m, 0.025f * x);
            float d = 1e-6f + m;
            float pd = exp2f(-0.98f * __log2f(d));
            float p = sqrtf(fmaf(x, pd, 2.0f)) - 1.41421356237f;
            tile[tt * 129 + tid] = p;
        }
        __syncthreads();
        for (int idx = tid; idx < nt * 128; idx += 128) {
            int row = idx / nt, col = idx - row * nt;
            out[(size_t)(b * NMELS + row) * NFRAMES + t0 + col] = tile[col * 129 + row];
        }
        __syncthreads();
    }
}

extern "C" void kernel_launch(void* const* d_in, const int* in_sizes, int n_in,
                              void* d_out, int out_size, void* d_ws, size_t ws_size,
                              hipStream_t stream) {
    const float* wav = (const float*)d_in[0];
    float* out = (float*)d_out;
    float* ws = (float*)d_ws;
    init_tables<<<1, 256, 0, stream>>>(ws);
    fft_mel_kernel<<<BATCH * NFRAMES, 256, 0, stream>>>(wav, ws);
    pcen_kernel<<<BATCH, 128, 0, stream>>>(ws, out);
}

// Round 3
// 345.288 us; speedup vs baseline: 2.6827x; 1.1441x over previous
//
#include <hip/hip_runtime.h>

#define PI_D 3.14159265358979323846

#define BATCH   64
#define LWAV    160000
#define NFFT    2048
#define HOP     512
#define NMELS   128
#define NFRAMES 313      // 1 + 160000/512
#define NCPLX   1024     // complex FFT size (real-pack)
#define PADW    1024     // NFFT/2

// PCEN chunked scan
#define NCH     8
#define CHLEN   40       // 7*40 + 33 = 313

// workspace layout (float offsets)
#define OFF_WIN  0        // 2048 window (natural order, read as float2)
#define OFF_TBL  2048     // float4[1024]: {kidx(bits), wA, wB, 0} digit-rev order
#define OFF_MFIN 6144     // 64*8*128 chunk-local final EMA states
#define OFF_MEL  71680    // NFRAMES * BATCH * NMELS  (t-major mel buffer)

// complex LDS pad: +1 float2 per 16 (breaks power-of-2 stride conflicts)
#define PC(i) ((i) + ((i) >> 4))
#define LDSC (NCPLX + NCPLX / 16)   // 1088 float2

__host__ __device__ __forceinline__ int digitrev10(int a) {
    return ((a & 3) << 8) | (((a >> 2) & 3) << 6) | (((a >> 4) & 3) << 4) |
           (((a >> 6) & 3) << 2) | ((a >> 8) & 3);
}

// 12 blocks: 0-7 window slices, 8-11 filterbank quarters.
__global__ __launch_bounds__(256) void init_tables(float* __restrict__ ws) {
    __shared__ double fpts[130];
    const int tid = threadIdx.x;
    const int blk = blockIdx.x;
    if (blk < 8) {
        int i = blk * 256 + tid;
        double w = 0.5 - 0.5 * cos(2.0 * PI_D * (double)i / (double)NFFT);
        ws[OFF_WIN + i] = (float)w;
        return;
    }
    if (tid < 130) {
        double mlo = 2595.0 * log10(1.0 + 20.0 / 700.0);
        double mhi = 2595.0 * log10(1.0 + 16000.0 / 700.0);
        double m = mlo + (mhi - mlo) * (double)tid / 129.0;
        fpts[tid] = 700.0 * (pow(10.0, m / 2595.0) - 1.0);
    }
    __syncthreads();
    float4* tbl = (float4*)(ws + OFF_TBL);
    int a = (blk - 8) * 256 + tid;
    {
        int k = digitrev10(a);
        double fhz = (double)k * 15.625;  // (SR/2)/1024 exact
        float wa = 0.f, wb = 0.f;
        int ka = 0, kb = 0;
        int kf = -1;
        for (int i = 0; i < 130; i++) kf += (fpts[i] <= fhz) ? 1 : 0;
        if (kf >= 0 && kf <= 127) {
            double down = (fhz - fpts[kf]) / (fpts[kf + 1] - fpts[kf]);
            double up   = (fpts[kf + 2] - fhz) / (fpts[kf + 2] - fpts[kf + 1]);
            double w = down < up ? down : up;
            if (w > 0.0) { wa = (float)w; ka = kf; }
        }
        int km = kf - 1;
        if (km >= 0 && km <= 127) {
            double down = (fhz - fpts[km]) / (fpts[km + 1] - fpts[km]);
            double up   = (fpts[km + 2] - fhz) / (fpts[km + 2] - fpts[km + 1]);
            double w = down < up ? down : up;
            if (w > 0.0) { wb = (float)w; kb = km; }
        }
        float4 v;
        v.x = __int_as_float(ka | (kb << 16));
        v.y = wa; v.z = wb; v.w = 0.f;
        tbl[a] = v;
    }
}

// In-place radix-4 DIF stage on float2 LDS (1 butterfly/thread, 256 threads).
template <int LOG2Q>
__device__ __forceinline__ void r4_stage(float2* __restrict__ Z, int tid) {
    const int Q = 1 << LOG2Q;
    const int L = 4 * Q;
    int j = tid & (Q - 1);
    int p = ((tid >> LOG2Q) << (LOG2Q + 2)) + j;
    int i0 = PC(p), i1 = PC(p + Q), i2 = PC(p + 2 * Q), i3 = PC(p + 3 * Q);
    float2 a0 = Z[i0], a1 = Z[i1], a2 = Z[i2], a3 = Z[i3];
    float t0r = a0.x + a2.x, t0i = a0.y + a2.y;
    float t1r = a0.x - a2.x, t1i = a0.y - a2.y;
    float t2r = a1.x + a3.x, t2i = a1.y + a3.y;
    float t3r = a1.x - a3.x, t3i = a1.y - a3.y;
    float ang = (-2.0f * 3.14159265358979f / (float)L) * (float)j;
    float s1, c1;
    __sincosf(ang, &s1, &c1);
    float c2 = c1 * c1 - s1 * s1, s2 = 2.f * c1 * s1;       // W^2
    float c3 = c1 * c2 - s1 * s2, s3 = c1 * s2 + s1 * c2;   // W^3
    float2 y0, y1, y2, y3;
    y0.x = t0r + t2r; y0.y = t0i + t2i;
    float u1r = t1r + t3i, u1i = t1i - t3r;                  // t1 - i*t3
    y1.x = u1r * c1 - u1i * s1; y1.y = u1r * s1 + u1i * c1;
    float u2r = t0r - t2r, u2i = t0i - t2i;
    y2.x = u2r * c2 - u2i * s2; y2.y = u2r * s2 + u2i * c2;
    float u3r = t1r - t3i, u3i = t1i + t3r;                  // t1 + i*t3
    y3.x = u3r * c3 - u3i * s3; y3.y = u3r * s3 + u3i * c3;
    Z[i0] = y0; Z[i1] = y1; Z[i2] = y2; Z[i3] = y3;
}

// One block per (b, t) frame: window+pack -> 1024-pt radix-4 DIF FFT in LDS
// -> real-FFT untwist -> power -> sparse mel scatter -> 128 mel out (t-major).
__global__ __launch_bounds__(256, 8) void fft_mel_kernel(const float* __restrict__ wav,
                                                         float* __restrict__ ws) {
    __shared__ float2 Z[LDSC];
    __shared__ float smel[NMELS];
    const int tid = threadIdx.x;
    const int blk = blockIdx.x;
    const int b = blk / NFRAMES;
    const int t = blk - b * NFRAMES;
    const float* __restrict__ src = wav + (size_t)b * LWAV;
    const int base = t * HOP - PADW;   // always even
    const float2* __restrict__ win2 = (const float2*)(ws + OFF_WIN);

    if (base >= 0 && base + NFFT <= LWAV) {
        const float2* __restrict__ s2 = (const float2*)(src + base);
#pragma unroll
        for (int q = 0; q < 4; q++) {
            int n = tid + q * 256;
            float2 xv = s2[n];
            float2 wv = win2[n];
            float2 z; z.x = xv.x * wv.x; z.y = xv.y * wv.y;
            Z[PC(n)] = z;
        }
    } else {
#pragma unroll
        for (int q = 0; q < 4; q++) {
            int n = tid + q * 256;
            int i0 = base + 2 * n, i1 = i0 + 1;
            i0 = i0 < 0 ? -i0 : i0; i0 = i0 >= LWAV ? 2 * LWAV - 2 - i0 : i0;
            i1 = i1 < 0 ? -i1 : i1; i1 = i1 >= LWAV ? 2 * LWAV - 2 - i1 : i1;
            float2 wv = win2[n];
            float2 z; z.x = src[i0] * wv.x; z.y = src[i1] * wv.y;
            Z[PC(n)] = z;
        }
    }
    if (tid < NMELS) smel[tid] = 0.f;
    __syncthreads();

    r4_stage<8>(Z, tid); __syncthreads();
    r4_stage<6>(Z, tid); __syncthreads();
    r4_stage<4>(Z, tid); __syncthreads();
    r4_stage<2>(Z, tid); __syncthreads();
    r4_stage<0>(Z, tid); __syncthreads();

    // Untwist + power + mel scatter. LDS addr a holds Z[digitrev10(a)].
    const float4* __restrict__ tbl = (const float4*)(ws + OFF_TBL);
#pragma unroll
    for (int q = 0; q < 4; q++) {
        int a = tid + q * 256;
        int k = digitrev10(a);
        int kp = (NCPLX - k) & (NCPLX - 1);
        int pa = digitrev10(kp);
        float2 za = Z[PC(a)];
        float2 zp = Z[PC(pa)];
        float Ar = 0.5f * (za.x + zp.x), Ai = 0.5f * (za.y - zp.y);
        float Or = 0.5f * (za.y + zp.y), Oi = -0.5f * (za.x - zp.x);
        float ang = (-3.14159265358979f / (float)NCPLX) * (float)k;
        float s, c;
        __sincosf(ang, &s, &c);
        float Xr = Ar + c * Or - s * Oi;
        float Xi = Ai + c * Oi + s * Or;
        float pw = Xr * Xr + Xi * Xi;
        float4 tb = tbl[a];
        int kk = __float_as_int(tb.x);
        atomicAdd(&smel[kk & 0xffff], pw * tb.y);
        atomicAdd(&smel[kk >> 16],    pw * tb.z);
    }
    __syncthreads();
    if (tid < NMELS) {
        ws[OFF_MEL + (size_t)t * (BATCH * NMELS) + b * NMELS + tid] = smel[tid];
    }
}

// Phase 1: per-(b,chunk) local EMA with zero init; write final state.
__global__ __launch_bounds__(128) void pcen_scan1(float* __restrict__ ws) {
    const int bx = blockIdx.x;
    const int b = bx >> 3, c = bx & 7;
    const int tid = threadIdx.x;
    const int t0 = c * CHLEN;
    const int len = (c == NCH - 1) ? (NFRAMES - t0) : CHLEN;
    const float* __restrict__ mel = ws + OFF_MEL + b * NMELS + tid;
    float m = 0.f;
#pragma unroll 8
    for (int t = 0; t < len; t++) {
        float x = mel[(size_t)(t0 + t) * (BATCH * NMELS)];
        m = fmaf(0.975f, m, 0.025f * x);
    }
    ws[OFF_MFIN + (b * NCH + c) * NMELS + tid] = m;
}

// Phase 2: fold incoming state, recompute chunk, emit transposed output.
__global__ __launch_bounds__(128) void pcen_scan2(const float* __restrict__ ws,
                                                  float* __restrict__ out) {
    __shared__ float tile[CHLEN * 129];
    const int bx = blockIdx.x;
    const int b = bx >> 3, c = bx & 7;
    const int tid = threadIdx.x;
    const int t0 = c * CHLEN;
    const int len = (c == NCH - 1) ? (NFRAMES - t0) : CHLEN;
    // Ap = 0.975^40 (f64 then cast; exact chunk-combine constant)
    double Apd = 1.0;
    for (int i = 0; i < CHLEN; i++) Apd *= 0.975;
    const float Ap = (float)Apd;
    float m = 0.f;
    const float* __restrict__ mfin = ws + OFF_MFIN + b * NCH * NMELS + tid;
    for (int cc = 0; cc < c; cc++) m = fmaf(Ap, m, mfin[cc * NMELS]);
    const float* __restrict__ mel = ws + OFF_MEL + b * NMELS + tid;
    for (int t = 0; t < len; t++) {
        float x = mel[(size_t)(t0 + t) * (BATCH * NMELS)];
        m = fmaf(0.975f, m, 0.025f * x);
        float d = 1e-6f + m;
        float pd = exp2f(-0.98f * __log2f(d));
        float p = sqrtf(fmaf(x, pd, 2.0f)) - 1.41421356237f;
        tile[t * 129 + tid] = p;
    }
    __syncthreads();
    for (int idx = tid; idx < len * 128; idx += 128) {
        int row = idx / len, col = idx - row * len;
        out[(size_t)(b * NMELS + row) * NFRAMES + t0 + col] = tile[col * 129 + row];
    }
}

extern "C" void kernel_launch(void* const* d_in, const int* in_sizes, int n_in,
                              void* d_out, int out_size, void* d_ws, size_t ws_size,
                              hipStream_t stream) {
    const float* wav = (const float*)d_in[0];
    float* out = (float*)d_out;
    float* ws = (float*)d_ws;
    init_tables<<<12, 256, 0, stream>>>(ws);
    fft_mel_kernel<<<BATCH * NFRAMES, 256, 0, stream>>>(wav, ws);
    pcen_scan1<<<BATCH * NCH, 128, 0, stream>>>(ws);
    pcen_scan2<<<BATCH * NCH, 128, 0, stream>>>(ws, out);
}